// Round 3
// baseline (160.654 us; speedup 1.0000x reference)
//
#include <hip/hip_runtime.h>

// DCNv1 forward on MI355X, bf16 MFMA, round 3.
// B=8, C=128, H=W=64, O=128, 3x3, pad=1 -> Ho=Wo=64.
// Pass 1: x -> x_t[B][H][W][C] bf16.  Pass 2: wgt -> w_t[O][tap][C] bf16.
// Pass 3: grid 1024 = (b, ho, wo-half). Block tile M=32(wo) x N=128(o).
//   Wave (mi,nh) = 16 wo x 64 o, 16 acc VGPRs. 4 blocks/CU (LDS 38.2KB, VGPR<=128).
//   K-loop: 9 taps; per tap stage w_t tap-slice (32KB) to LDS, A-frags built in
//   registers from coalesced 16B gathers of x_t. Epilogue: LDS transpose ->
//   64B-contiguous stores per lane (kills the 2.6x write amplification).

#define BB 8
#define CC 128
#define HH 64
#define WW 64
#define OO 128
#define KTAPS 9
#define WLDS_STRIDE 136   // shorts; 272B rows: 16B-aligned, odd 16B-multiple

typedef __attribute__((ext_vector_type(8))) short bf16x8;
typedef __attribute__((ext_vector_type(4))) float f32x4;

__device__ __forceinline__ unsigned short f2bf(float f) {
    unsigned u = __float_as_uint(f);
    u += 0x7FFFu + ((u >> 16) & 1u);   // RNE
    return (unsigned short)(u >> 16);
}
__device__ __forceinline__ float bf2f(unsigned u16) {
    return __uint_as_float(u16 << 16);
}

// ---------------- Pass 1: x[B][C][H][W] f32 -> xt[B][H][W][C] bf16 ----------------
__global__ __launch_bounds__(256)
void transpose_x_kernel(const float* __restrict__ x, unsigned short* __restrict__ xt) {
    __shared__ float tile[WW * 132];               // [w][c], stride 132 dwords (8B-aligned rows)
    const int t = threadIdx.x;
    const int b = blockIdx.x >> 6;
    const int h = blockIdx.x & 63;
    const float* src = x + ((size_t)b * CC * HH + h) * WW;
    // phase 1: float4 coalesced reads; scalar LDS writes
    {
        const int wq = t & 15;         // 4-w group
        const int cb = t >> 4;         // c base (16 per iter)
#pragma unroll
        for (int it = 0; it < 8; ++it) {
            const int c = it * 16 + cb;
            const float4 v = *reinterpret_cast<const float4*>(src + (size_t)c * (HH * WW) + wq * 4);
            tile[(wq * 4 + 0) * 132 + c] = v.x;
            tile[(wq * 4 + 1) * 132 + c] = v.y;
            tile[(wq * 4 + 2) * 132 + c] = v.z;
            tile[(wq * 4 + 3) * 132 + c] = v.w;
        }
    }
    __syncthreads();
    // phase 2: b64 LDS reads (2-way max), pack 8 bf16, 16B coalesced writes
    unsigned short* dst = xt + ((size_t)b * HH + h) * WW * CC;
    {
        const int cg = t & 15;         // which 8-channel chunk
        const int wb = t >> 4;         // w base (16 per iter)
#pragma unroll
        for (int it = 0; it < 4; ++it) {
            const int w = it * 16 + wb;
            const float2 f0 = *reinterpret_cast<const float2*>(&tile[w * 132 + cg * 8 + 0]);
            const float2 f1 = *reinterpret_cast<const float2*>(&tile[w * 132 + cg * 8 + 2]);
            const float2 f2 = *reinterpret_cast<const float2*>(&tile[w * 132 + cg * 8 + 4]);
            const float2 f3 = *reinterpret_cast<const float2*>(&tile[w * 132 + cg * 8 + 6]);
            uint4 p;
            p.x = (unsigned)f2bf(f0.x) | ((unsigned)f2bf(f0.y) << 16);
            p.y = (unsigned)f2bf(f1.x) | ((unsigned)f2bf(f1.y) << 16);
            p.z = (unsigned)f2bf(f2.x) | ((unsigned)f2bf(f2.y) << 16);
            p.w = (unsigned)f2bf(f3.x) | ((unsigned)f2bf(f3.y) << 16);
            *reinterpret_cast<uint4*>(&dst[(size_t)w * CC + cg * 8]) = p;
        }
    }
}

// ---------------- Pass 2: wgt[O][C][3][3] f32 -> wt[O][tap][C] bf16 ----------------
__global__ __launch_bounds__(256)
void transpose_w_kernel(const float* __restrict__ wgt, unsigned short* __restrict__ wt) {
    const int id = blockIdx.x * 256 + threadIdx.x;   // 128*9*16 = 18432 items
    if (id >= OO * KTAPS * 16) return;
    const int cg  = id & 15;
    const int r   = id >> 4;
    const int tap = r % KTAPS;
    const int o   = r / KTAPS;
    const float* s = wgt + ((size_t)o * CC + cg * 8) * KTAPS + tap;
    unsigned u[4];
#pragma unroll
    for (int j = 0; j < 4; ++j) {
        const unsigned short lo = f2bf(s[(2 * j)     * KTAPS]);
        const unsigned short hi = f2bf(s[(2 * j + 1) * KTAPS]);
        u[j] = (unsigned)lo | ((unsigned)hi << 16);
    }
    *reinterpret_cast<uint4*>(&wt[((size_t)o * KTAPS + tap) * CC + cg * 8]) =
        make_uint4(u[0], u[1], u[2], u[3]);
}

// ---------------- Pass 3: fused DCN MFMA ----------------
__global__ __launch_bounds__(256, 4)
void dcn_mfma_kernel(const unsigned short* __restrict__ xt,
                     const unsigned short* __restrict__ wt,
                     const float* __restrict__ offset,
                     const float* __restrict__ bias,
                     float* __restrict__ out) {
    __shared__ __align__(16) unsigned short wlds[OO * WLDS_STRIDE];  // 34816 B
    __shared__ __align__(8)  float2 sLL[KTAPS * 32];                 // (ly, lx)   2304 B
    __shared__ __align__(4)  short2 sYX[KTAPS * 32];                 // (y0, x0)   1152 B

    const int t  = threadIdx.x;
    const int b  = blockIdx.x >> 7;
    const int ho = (blockIdx.x >> 1) & 63;
    const int mh = blockIdx.x & 1;         // wo half

    // ---- packed sampling records: 9 taps x 32 local wo ----
    for (int s = t; s < KTAPS * 32; s += 256) {
        const int k   = s >> 5;
        const int wol = s & 31;
        const int wo  = mh * 32 + wol;
        const int ki  = k / 3;
        const int kj  = k - ki * 3;
        const float dy = offset[(((size_t)b * 18 + 2 * k    ) * 64 + ho) * 64 + wo];
        const float dx = offset[(((size_t)b * 18 + 2 * k + 1) * 64 + ho) * 64 + wo];
        const float py = (float)(ho - 1 + ki) + dy;
        const float px = (float)(wo - 1 + kj) + dx;
        const float y0f = floorf(py);
        const float x0f = floorf(px);
        sLL[s] = make_float2(py - y0f, px - x0f);
        sYX[s] = make_short2((short)(int)y0f, (short)(int)x0f);
    }

    f32x4 acc[4];
#pragma unroll
    for (int nt = 0; nt < 4; ++nt) acc[nt] = (f32x4){0.f, 0.f, 0.f, 0.f};

    const int lane = t & 63;
    const int wave = t >> 6;
    const int mi   = wave & 1;    // which 16-wo m-tile of this block's 32
    const int nh   = wave >> 1;   // which 64-o half
    const int lm   = lane & 15;
    const int quad = lane >> 4;
    const char* xb = (const char*)(xt + (size_t)b * HH * WW * CC);

    __syncthreads();

    for (int tap = 0; tap < KTAPS; ++tap) {
        // ---- stage this tap's weights: wlds[o][c] ----
        {
            const int seg  = t & 15;
            const int orow = t >> 4;
#pragma unroll
            for (int i = 0; i < 8; ++i) {
                const int o = orow + i * 16;
                const uint4 v = *reinterpret_cast<const uint4*>(
                    wt + ((size_t)o * KTAPS + tap) * CC + seg * 8);
                *reinterpret_cast<uint4*>(&wlds[o * WLDS_STRIDE + seg * 8]) = v;
            }
        }

        // ---- reconstruct this lane's sampling record (reads pre-loop LDS, stable) ----
        const int rec = (tap << 5) + (mi << 4) + lm;
        const float2 ll = sLL[rec];
        const short2 yx = sYX[rec];
        const int y0 = yx.x, x0 = yx.y;
        const int y1 = y0 + 1, x1 = x0 + 1;
        const float ly = ll.x, lx = ll.y;
        const bool vy0 = ((unsigned)y0 < (unsigned)HH);
        const bool vy1 = ((unsigned)y1 < (unsigned)HH);
        const bool vx0 = ((unsigned)x0 < (unsigned)WW);
        const bool vx1 = ((unsigned)x1 < (unsigned)WW);
        const float w00 = (vy0 && vx0) ? (1.f - ly) * (1.f - lx) : 0.f;
        const float w01 = (vy0 && vx1) ? (1.f - ly) * lx         : 0.f;
        const float w10 = (vy1 && vx0) ? ly * (1.f - lx)         : 0.f;
        const float w11 = (vy1 && vx1) ? ly * lx                 : 0.f;
        const int cy0 = min(max(y0, 0), HH - 1);
        const int cy1 = min(max(y1, 0), HH - 1);
        const int cx0 = min(max(x0, 0), WW - 1);
        const int cx1 = min(max(x1, 0), WW - 1);
        const int o00 = ((cy0 << 6) + cx0) << 8;   // pixel * 128ch * 2B
        const int o01 = ((cy0 << 6) + cx1) << 8;
        const int o10 = ((cy1 << 6) + cx0) << 8;
        const int o11 = ((cy1 << 6) + cx1) << 8;

        __syncthreads();   // wlds staged

#pragma unroll
        for (int c0 = 0; c0 < CC; c0 += 32) {
            const int cb = (c0 + quad * 8) * 2;
            const uint4 v00 = *reinterpret_cast<const uint4*>(xb + o00 + cb);
            const uint4 v01 = *reinterpret_cast<const uint4*>(xb + o01 + cb);
            const uint4 v10 = *reinterpret_cast<const uint4*>(xb + o10 + cb);
            const uint4 v11 = *reinterpret_cast<const uint4*>(xb + o11 + cb);
            const unsigned* u00 = reinterpret_cast<const unsigned*>(&v00);
            const unsigned* u01 = reinterpret_cast<const unsigned*>(&v01);
            const unsigned* u10 = reinterpret_cast<const unsigned*>(&v10);
            const unsigned* u11 = reinterpret_cast<const unsigned*>(&v11);
            unsigned afu[4];
#pragma unroll
            for (int j = 0; j < 4; ++j) {
                const unsigned p00 = u00[j], p01 = u01[j], p10 = u10[j], p11 = u11[j];
                const float lo = w00 * bf2f(p00 & 0xFFFFu) + w01 * bf2f(p01 & 0xFFFFu)
                               + w10 * bf2f(p10 & 0xFFFFu) + w11 * bf2f(p11 & 0xFFFFu);
                const float hi = w00 * bf2f(p00 >> 16) + w01 * bf2f(p01 >> 16)
                               + w10 * bf2f(p10 >> 16) + w11 * bf2f(p11 >> 16);
                afu[j] = (unsigned)f2bf(lo) | ((unsigned)f2bf(hi) << 16);
            }
            const bf16x8 afrag = *reinterpret_cast<const bf16x8*>(afu);
#pragma unroll
            for (int nt = 0; nt < 4; ++nt) {
                const bf16x8 bfrag = *reinterpret_cast<const bf16x8*>(
                    &wlds[(nh * 64 + nt * 16 + lm) * WLDS_STRIDE + c0 + quad * 8]);
                acc[nt] = __builtin_amdgcn_mfma_f32_16x16x32_bf16(afrag, bfrag, acc[nt], 0, 0, 0);
            }
        }
        __syncthreads();   // compute done; next tap may restage
    }

    // ---- epilogue: per-wave LDS transpose -> 64B-contiguous stores ----
    // scratch: [o_local 64][wo 16 + 4pad] f32, stride 20 dwords, per-wave region
    float* scr = reinterpret_cast<float*>(wlds) + wave * (64 * 20);
#pragma unroll
    for (int nt = 0; nt < 4; ++nt) {
        const int o_l = nt * 16 + lm;
        f32x4 v = acc[nt];
        *reinterpret_cast<float4*>(&scr[o_l * 20 + quad * 4]) =
            make_float4(v[0], v[1], v[2], v[3]);
    }
    __syncthreads();
    {
        const int o = nh * 64 + lane;          // wait: lane spans 0..63, but this wave's
        // scratch holds o_l 0..63 of ITS half -> o = nh*64 + lane  (lane == o_l)
        const float bv = bias[o];
        float* op = out + (((size_t)(b * OO + o) * HH + ho) << 6) + mh * 32 + mi * 16;
        const float* sr = reinterpret_cast<const float*>(wlds) + wave * (64 * 20) + lane * 20;
#pragma unroll
        for (int j = 0; j < 4; ++j) {
            const float4 f = *reinterpret_cast<const float4*>(sr + j * 4);
            *reinterpret_cast<float4*>(op + j * 4) =
                make_float4(f.x + bv, f.y + bv, f.z + bv, f.w + bv);
        }
    }
}

extern "C" void kernel_launch(void* const* d_in, const int* in_sizes, int n_in,
                              void* d_out, int out_size, void* d_ws, size_t ws_size,
                              hipStream_t stream) {
    const float* x      = (const float*)d_in[0];
    const float* offset = (const float*)d_in[1];
    const float* wgt    = (const float*)d_in[2];
    const float* bias   = (const float*)d_in[3];
    float* out = (float*)d_out;

    unsigned short* xt = (unsigned short*)d_ws;                       // 8 MiB
    unsigned short* wt = xt + (size_t)BB * HH * WW * CC;              // +288 KiB

    hipLaunchKernelGGL(transpose_w_kernel, dim3((OO * KTAPS * 16 + 255) / 256), dim3(256),
                       0, stream, wgt, wt);
    hipLaunchKernelGGL(transpose_x_kernel, dim3(BB * HH), dim3(256), 0, stream, x, xt);
    hipLaunchKernelGGL(dcn_mfma_kernel, dim3(BB * HH * 2), dim3(256), 0, stream,
                       xt, wt, offset, bias, out);
}

// Round 4
// 132.637 us; speedup vs baseline: 1.2112x; 1.2112x over previous
//
#include <hip/hip_runtime.h>

// DCNv1 forward on MI355X, bf16 MFMA, round 4: barrier-free K-loop.
// B=8, C=128, H=W=64, O=128, 3x3, pad=1 -> Ho=Wo=64.
//
// prep_kernel (1 launch): blocks 0..511  : x[B][C][H][W] f32 -> xt[B][H][W][C] bf16
//                         blocks 512..583: wgt -> wpk in MFMA B-fragment order:
//                           frag = (tap*4 + c0q)*8 + nt ; wpk[frag*64 + lane]*16B,
//                           lane: n=lane&15 (o=nt*16+n), k-chunk=lane>>4 (c=c0q*32+q*8..+7)
// dcn_mfma_kernel: grid 512=(b,ho), 256 thr = 4 waves. Wave = 16-wo m-tile x N=128.
//   K-loop (9 taps x 4 c0): A-frag built in regs from 4 scattered uint4 corner loads
//   (double-buffered across c0), B-frags coalesced from global wpk (L2-hot).
//   ZERO barriers in the K-loop. Epilogue: LDS-transpose -> 64B/lane stores.

#define BB 8
#define CC 128
#define HH 64
#define WW 64
#define OO 128
#define KTAPS 9

typedef __attribute__((ext_vector_type(8))) short bf16x8;
typedef __attribute__((ext_vector_type(4))) float f32x4;

__device__ __forceinline__ unsigned short f2bf(float f) {
    unsigned u = __float_as_uint(f);
    u += 0x7FFFu + ((u >> 16) & 1u);   // RNE
    return (unsigned short)(u >> 16);
}
#if __has_builtin(__builtin_amdgcn_cvt_pk_bf16_f32)
typedef __attribute__((ext_vector_type(2))) __bf16 bf16x2_t;
__device__ __forceinline__ unsigned pack2bf(float lo, float hi) {
    bf16x2_t v = __builtin_amdgcn_cvt_pk_bf16_f32(lo, hi);
    unsigned r;
    __builtin_memcpy(&r, &v, 4);
    return r;
}
#else
__device__ __forceinline__ unsigned pack2bf(float lo, float hi) {
    return (unsigned)f2bf(lo) | ((unsigned)f2bf(hi) << 16);
}
#endif
__device__ __forceinline__ float bflo(unsigned p) { return __uint_as_float(p << 16); }
__device__ __forceinline__ float bfhi(unsigned p) { return __uint_as_float(p & 0xFFFF0000u); }

// ---------------- prep: transpose x + pack weights (one launch) ----------------
__global__ __launch_bounds__(256)
void prep_kernel(const float* __restrict__ x, const float* __restrict__ wgt,
                 unsigned short* __restrict__ xt, unsigned short* __restrict__ wpk) {
    const int t = threadIdx.x;
    if (blockIdx.x < 512) {
        // ---- x[B][C][H][W] f32 -> xt[B][H][W][C] bf16 ----
        __shared__ float tile[WW * 132];
        const int b = blockIdx.x >> 6;
        const int h = blockIdx.x & 63;
        const float* src = x + ((size_t)b * CC * HH + h) * WW;
        {
            const int wq = t & 15;
            const int cb = t >> 4;
#pragma unroll
            for (int it = 0; it < 8; ++it) {
                const int c = it * 16 + cb;
                const float4 v = *reinterpret_cast<const float4*>(src + (size_t)c * (HH * WW) + wq * 4);
                tile[(wq * 4 + 0) * 132 + c] = v.x;
                tile[(wq * 4 + 1) * 132 + c] = v.y;
                tile[(wq * 4 + 2) * 132 + c] = v.z;
                tile[(wq * 4 + 3) * 132 + c] = v.w;
            }
        }
        __syncthreads();
        unsigned short* dst = xt + ((size_t)b * HH + h) * WW * CC;
        {
            const int cg = t & 15;
            const int wb = t >> 4;
#pragma unroll
            for (int it = 0; it < 4; ++it) {
                const int w = it * 16 + wb;
                const float* tp = &tile[w * 132 + cg * 8];
                uint4 p;
                p.x = pack2bf(tp[0], tp[1]);
                p.y = pack2bf(tp[2], tp[3]);
                p.z = pack2bf(tp[4], tp[5]);
                p.w = pack2bf(tp[6], tp[7]);
                *reinterpret_cast<uint4*>(&dst[(size_t)w * CC + cg * 8]) = p;
            }
        }
    } else {
        // ---- wgt[O][C][3][3] f32 -> wpk fragment-ordered bf16 ----
        const int id   = (blockIdx.x - 512) * 256 + t;   // 0..18431
        const int lane = id & 63;
        const int frag = id >> 6;                        // (tap*4 + c0q)*8 + nt
        const int nt   = frag & 7;
        const int c0q  = (frag >> 3) & 3;
        const int tap  = frag >> 5;
        const int o    = (nt << 4) + (lane & 15);
        const int c    = (c0q << 5) + ((lane >> 4) << 3);
        const float* s = wgt + ((size_t)o * CC + c) * KTAPS + tap;
        unsigned u[4];
#pragma unroll
        for (int j = 0; j < 4; ++j)
            u[j] = pack2bf(s[(2 * j) * KTAPS], s[(2 * j + 1) * KTAPS]);
        *reinterpret_cast<uint4*>(wpk + (size_t)frag * 512 + lane * 8) =
            make_uint4(u[0], u[1], u[2], u[3]);
    }
}

// ---------------- main: fused DCN MFMA, barrier-free K-loop ----------------
__global__ __launch_bounds__(256, 2)
void dcn_mfma_kernel(const unsigned short* __restrict__ xt,
                     const unsigned short* __restrict__ wpk,
                     const float* __restrict__ offset,
                     const float* __restrict__ bias,
                     float* __restrict__ out) {
    // 40960 B: records (6912 B) during K-loop, epilogue scratch after the barrier
    __shared__ __align__(16) float smem_f[4 * 128 * 20];
    float2* sLL = reinterpret_cast<float2*>(smem_f);           // [576] (ly,lx)
    short2* sYX = reinterpret_cast<short2*>(smem_f + 1152);    // [576] (y0,x0)

    const int t  = threadIdx.x;
    const int b  = blockIdx.x >> 6;
    const int ho = blockIdx.x & 63;

    // ---- sampling records: 9 taps x 64 wo ----
    for (int s = t; s < KTAPS * 64; s += 256) {
        const int k  = s >> 6;
        const int wo = s & 63;
        const int ki = k / 3;
        const int kj = k - ki * 3;
        const float dy = offset[(((size_t)b * 18 + 2 * k    ) * 64 + ho) * 64 + wo];
        const float dx = offset[(((size_t)b * 18 + 2 * k + 1) * 64 + ho) * 64 + wo];
        const float py = (float)(ho - 1 + ki) + dy;
        const float px = (float)(wo - 1 + kj) + dx;
        const float y0f = floorf(py);
        const float x0f = floorf(px);
        sLL[s] = make_float2(py - y0f, px - x0f);
        sYX[s] = make_short2((short)(int)y0f, (short)(int)x0f);
    }
    __syncthreads();   // the ONLY barrier before the epilogue

    f32x4 acc[8];
#pragma unroll
    for (int nt = 0; nt < 8; ++nt) acc[nt] = (f32x4){0.f, 0.f, 0.f, 0.f};

    const int lane = t & 63;
    const int wave = t >> 6;          // m-tile (16 wo)
    const int lm   = lane & 15;
    const int quad = lane >> 4;
    const int q16  = quad * 16;
    const int lane16 = lane * 16;
    const char* xb = (const char*)(xt + (size_t)b * HH * WW * CC);
    const char* wb = (const char*)wpk;

    for (int tap = 0; tap < KTAPS; ++tap) {
        // decode this lane's record
        const int rec = (tap << 6) + (wave << 4) + lm;
        const float2 ll = sLL[rec];
        const short2 yx = sYX[rec];
        const int y0 = yx.x, x0 = yx.y;
        const int y1 = y0 + 1, x1 = x0 + 1;
        const float ly = ll.x, lx = ll.y;
        const bool vy0 = ((unsigned)y0 < (unsigned)HH);
        const bool vy1 = ((unsigned)y1 < (unsigned)HH);
        const bool vx0 = ((unsigned)x0 < (unsigned)WW);
        const bool vx1 = ((unsigned)x1 < (unsigned)WW);
        const float w00 = (vy0 && vx0) ? (1.f - ly) * (1.f - lx) : 0.f;
        const float w01 = (vy0 && vx1) ? (1.f - ly) * lx         : 0.f;
        const float w10 = (vy1 && vx0) ? ly * (1.f - lx)         : 0.f;
        const float w11 = (vy1 && vx1) ? ly * lx                 : 0.f;
        const int cy0 = min(max(y0, 0), HH - 1);
        const int cy1 = min(max(y1, 0), HH - 1);
        const int cx0 = min(max(x0, 0), WW - 1);
        const int cx1 = min(max(x1, 0), WW - 1);
        const char* base00 = xb + ((((cy0 << 6) + cx0) << 8) + q16);
        const char* base01 = xb + ((((cy0 << 6) + cx1) << 8) + q16);
        const char* base10 = xb + ((((cy1 << 6) + cx0) << 8) + q16);
        const char* base11 = xb + ((((cy1 << 6) + cx1) << 8) + q16);

        // A corner loads for c0q=0
        uint4 a00 = *reinterpret_cast<const uint4*>(base00);
        uint4 a01 = *reinterpret_cast<const uint4*>(base01);
        uint4 a10 = *reinterpret_cast<const uint4*>(base10);
        uint4 a11 = *reinterpret_cast<const uint4*>(base11);

#pragma unroll
        for (int c0q = 0; c0q < 4; ++c0q) {
            // B-frags: coalesced, L2-hot
            uint4 bfr[8];
            const char* wrow = wb + ((((tap << 5) + (c0q << 3))) << 10) + lane16;
#pragma unroll
            for (int nt = 0; nt < 8; ++nt)
                bfr[nt] = *reinterpret_cast<const uint4*>(wrow + (nt << 10));
            // prefetch next c0q's A corners
            uint4 n00, n01, n10, n11;
            if (c0q < 3) {
                const int cb = (c0q + 1) << 6;
                n00 = *reinterpret_cast<const uint4*>(base00 + cb);
                n01 = *reinterpret_cast<const uint4*>(base01 + cb);
                n10 = *reinterpret_cast<const uint4*>(base10 + cb);
                n11 = *reinterpret_cast<const uint4*>(base11 + cb);
            }
            // bilinear blend -> bf16 A-frag
            const unsigned* u00 = reinterpret_cast<const unsigned*>(&a00);
            const unsigned* u01 = reinterpret_cast<const unsigned*>(&a01);
            const unsigned* u10 = reinterpret_cast<const unsigned*>(&a10);
            const unsigned* u11 = reinterpret_cast<const unsigned*>(&a11);
            unsigned afu[4];
#pragma unroll
            for (int j = 0; j < 4; ++j) {
                const float rl = w00 * bflo(u00[j]) + w01 * bflo(u01[j])
                               + w10 * bflo(u10[j]) + w11 * bflo(u11[j]);
                const float rh = w00 * bfhi(u00[j]) + w01 * bfhi(u01[j])
                               + w10 * bfhi(u10[j]) + w11 * bfhi(u11[j]);
                afu[j] = pack2bf(rl, rh);
            }
            bf16x8 afrag;
            __builtin_memcpy(&afrag, afu, 16);
#pragma unroll
            for (int nt = 0; nt < 8; ++nt) {
                bf16x8 bfrag;
                __builtin_memcpy(&bfrag, &bfr[nt], 16);
                acc[nt] = __builtin_amdgcn_mfma_f32_16x16x32_bf16(afrag, bfrag, acc[nt], 0, 0, 0);
            }
            if (c0q < 3) { a00 = n00; a01 = n01; a10 = n10; a11 = n11; }
        }
    }

    // ---- epilogue: per-wave LDS transpose -> 64B-contiguous stores ----
    __syncthreads();   // records dead; scratch overlay safe
    float* scr = smem_f + wave * (128 * 20);
#pragma unroll
    for (int nt = 0; nt < 8; ++nt) {
        const int o_l = (nt << 4) + lm;
        *reinterpret_cast<float4*>(&scr[o_l * 20 + (quad << 2)]) =
            make_float4(acc[nt][0], acc[nt][1], acc[nt][2], acc[nt][3]);
    }
#pragma unroll
    for (int h = 0; h < 2; ++h) {
        const int o = (h << 6) + lane;
        const float bv = bias[o];
        float* op = out + (((size_t)(b * OO + o) * HH + ho) << 6) + (wave << 4);
        const float* sr = scr + o * 20;
#pragma unroll
        for (int j = 0; j < 4; ++j) {
            const float4 f = *reinterpret_cast<const float4*>(sr + j * 4);
            *reinterpret_cast<float4*>(op + j * 4) =
                make_float4(f.x + bv, f.y + bv, f.z + bv, f.w + bv);
        }
    }
}

extern "C" void kernel_launch(void* const* d_in, const int* in_sizes, int n_in,
                              void* d_out, int out_size, void* d_ws, size_t ws_size,
                              hipStream_t stream) {
    const float* x      = (const float*)d_in[0];
    const float* offset = (const float*)d_in[1];
    const float* wgt    = (const float*)d_in[2];
    const float* bias   = (const float*)d_in[3];
    float* out = (float*)d_out;

    unsigned short* xt  = (unsigned short*)d_ws;                  // 8 MiB
    unsigned short* wpk = xt + (size_t)BB * HH * WW * CC;         // +288 KiB

    hipLaunchKernelGGL(prep_kernel, dim3(512 + 72), dim3(256), 0, stream, x, wgt, xt, wpk);
    hipLaunchKernelGGL(dcn_mfma_kernel, dim3(BB * HH), dim3(256), 0, stream,
                       xt, wpk, offset, bias, out);
}